// Round 1
// baseline (168.107 us; speedup 1.0000x reference)
//
#include <hip/hip_runtime.h>
#include <hip/hip_bf16.h>

#define B_   128
#define LSEQ 8194
#define NPOS 2048
#define DDIM 128

typedef __attribute__((ext_vector_type(8))) short bf16x8;
typedef __attribute__((ext_vector_type(4))) float f32x4;

static __device__ __forceinline__ short f2bf(float f){
    union { __hip_bfloat16 h; short s; } u; u.h = __float2bfloat16(f); return u.s;
}
static __device__ __forceinline__ float bf2f(unsigned int s){
    union { float f; unsigned int u; } u; u.u = s << 16; return u.f;
}
static __device__ __forceinline__ float tanh_fast(float x){
    float ex = __expf(2.0f * x);
    return 1.0f - __fdividef(2.0f, ex + 1.0f);
}

// K0: conv -> y2 bf16 [b][n][k], k = c*4 + s, value = relu(sum_k dot_k[letter_k][c])
__global__ __launch_bounds__(256) void k0_conv(const int* __restrict__ seq,
        const float* __restrict__ emb, const float* __restrict__ cw,
        const float* __restrict__ cb, unsigned short* __restrict__ ws_y)
{
    __shared__ __hip_bfloat162 tbl[3][26][16];   // [tap][letter][c-pair]
    int tid = threadIdx.x;
    for (int idx = tid; idx < 3*26*16; idx += 256){
        int k = idx / (26*16);
        int rem = idx - k*26*16;
        int l = rem >> 4;
        int cp = rem & 15;
        int c0 = cp*2;
        float v0 = 0.f, v1 = 0.f;
        #pragma unroll
        for (int i = 0; i < 5; i++){
            float e = emb[l*5 + i];
            v0 += cw[(c0*5 + i)*3 + k] * e;
            v1 += cw[((c0+1)*5 + i)*3 + k] * e;
        }
        if (k == 2){ v0 += cb[c0]; v1 += cb[c0+1]; }
        tbl[k][l][cp] = __float22bfloat162_rn(make_float2(v0, v1));
    }
    __syncthreads();
    int wave = tid >> 6, lane = tid & 63;
    int ns = lane >> 4, kg = lane & 15;
    int b  = blockIdx.x >> 2;
    int n0 = (blockIdx.x & 3) * 512;
    const int* sb = seq + b * LSEQ;
    for (int it = 0; it < 32; it++){
        int n = n0 + it*16 + wave*4 + ns;
        float res[8];
        #pragma unroll
        for (int s = 0; s < 4; s++){
            int p = s*2048 + n;
            int l1 = sb[p], l2 = sb[p+1], l3 = sb[p+2];
            float2 g0 = __bfloat1622float2(tbl[0][l1][kg]);
            float2 g1 = __bfloat1622float2(tbl[1][l2][kg]);
            float2 g2 = __bfloat1622float2(tbl[2][l3][kg]);
            res[s]   = fmaxf(g0.x + g1.x + g2.x, 0.f);   // c = 2*kg,   k = kg*8 + s
            res[4+s] = fmaxf(g0.y + g1.y + g2.y, 0.f);   // c = 2*kg+1, k = kg*8 + 4 + s
        }
        union { __hip_bfloat162 h; unsigned int u; } p0,p1,p2,p3;
        p0.h = __float22bfloat162_rn(make_float2(res[0],res[1]));
        p1.h = __float22bfloat162_rn(make_float2(res[2],res[3]));
        p2.h = __float22bfloat162_rn(make_float2(res[4],res[5]));
        p3.h = __float22bfloat162_rn(make_float2(res[6],res[7]));
        uint4 o; o.x = p0.u; o.y = p1.u; o.z = p2.u; o.w = p3.u;
        *((uint4*)(ws_y + (((size_t)b*NPOS + n)*DDIM + kg*8))) = o;
    }
}

// K1: e[b,n] = v_a . tanh(W_a @ y2[b]) via bf16 MFMA; W frags held in registers
__global__ __launch_bounds__(256, 2) void k1_gemm(const unsigned short* __restrict__ ws_y,
        const float* __restrict__ Wa, const float* __restrict__ va,
        float* __restrict__ ws_e)
{
    __shared__ unsigned short ylds[64][136];   // [n][k], pad 8 bf16 to break conflicts
    __shared__ float va_lds[128];
    int tid = threadIdx.x;
    int wave = tid >> 6, lane = tid & 63;
    int m = lane & 15, q = lane >> 4;
    int b = blockIdx.y;
    int n0 = blockIdx.x * 512;
    if (tid < 128) va_lds[tid] = va[tid];

    // A-frags: lane holds W[dt*16+m][ki*32 + q*8 + j], j=0..7
    bf16x8 wf[8][4];
    #pragma unroll
    for (int dt = 0; dt < 8; dt++){
        #pragma unroll
        for (int ki = 0; ki < 4; ki++){
            const float* wp = Wa + (dt*16 + m)*128 + ki*32 + q*8;
            float4 a  = *((const float4*)wp);
            float4 b4 = *((const float4*)(wp + 4));
            bf16x8 f;
            f[0]=f2bf(a.x);  f[1]=f2bf(a.y);  f[2]=f2bf(a.z);  f[3]=f2bf(a.w);
            f[4]=f2bf(b4.x); f[5]=f2bf(b4.y); f[6]=f2bf(b4.z); f[7]=f2bf(b4.w);
            wf[dt][ki] = f;
        }
    }
    __syncthreads();

    for (int sub = 0; sub < 8; sub++){
        #pragma unroll
        for (int j = 0; j < 4; j++){
            int idx = tid + j*256;
            int row = idx >> 4, col = idx & 15;
            const uint4* src = (const uint4*)(ws_y +
                (((size_t)b*NPOS + n0 + sub*64 + row)*DDIM + col*8));
            *((uint4*)&ylds[row][col*8]) = *src;
        }
        __syncthreads();
        f32x4 acc[8];
        #pragma unroll
        for (int dt = 0; dt < 8; dt++) acc[dt] = (f32x4){0.f,0.f,0.f,0.f};
        #pragma unroll
        for (int ki = 0; ki < 4; ki++){
            bf16x8 bfrag = *((const bf16x8*)&ylds[wave*16 + m][ki*32 + q*8]);
            #pragma unroll
            for (int dt = 0; dt < 8; dt++)
                acc[dt] = __builtin_amdgcn_mfma_f32_16x16x32_bf16(wf[dt][ki], bfrag, acc[dt], 0, 0, 0);
        }
        float epart = 0.f;
        #pragma unroll
        for (int dt = 0; dt < 8; dt++){
            float4 vv = *((const float4*)&va_lds[dt*16 + q*4]);
            epart += vv.x * tanh_fast(acc[dt][0]);
            epart += vv.y * tanh_fast(acc[dt][1]);
            epart += vv.z * tanh_fast(acc[dt][2]);
            epart += vv.w * tanh_fast(acc[dt][3]);
        }
        epart += __shfl_xor(epart, 16);
        epart += __shfl_xor(epart, 32);
        if (lane < 16)
            ws_e[b*NPOS + n0 + sub*64 + wave*16 + lane] = epart;
        __syncthreads();
    }
}

// K2: softmax stats per b + zero d_out
__global__ __launch_bounds__(256) void k2_softmax(const float* __restrict__ ws_e,
        float* __restrict__ stats, float* __restrict__ out)
{
    int b = blockIdx.x, tid = threadIdx.x;
    if (tid < 128) out[b*128 + tid] = 0.f;
    const float* e = ws_e + b*NPOS;
    int wave = tid >> 6, lane = tid & 63;
    __shared__ float red[4], red2[4];
    float mx = -1e30f;
    for (int i = tid; i < NPOS; i += 256) mx = fmaxf(mx, e[i]);
    #pragma unroll
    for (int off = 32; off >= 1; off >>= 1) mx = fmaxf(mx, __shfl_xor(mx, off));
    if (lane == 0) red[wave] = mx;
    __syncthreads();
    mx = fmaxf(fmaxf(red[0], red[1]), fmaxf(red[2], red[3]));
    float s = 0.f;
    for (int i = tid; i < NPOS; i += 256) s += __expf(e[i] - mx);
    #pragma unroll
    for (int off = 32; off >= 1; off >>= 1) s += __shfl_xor(s, off);
    if (lane == 0) red2[wave] = s;
    __syncthreads();
    if (tid == 0){
        s = red2[0] + red2[1] + red2[2] + red2[3];
        stats[b*2] = mx;
        stats[b*2+1] = 1.0f / s;
    }
}

// K3: ctx[b,d] = sum_n softmax(e)[n] * y2[b,d,n]
__global__ __launch_bounds__(256) void k3_ctx(const unsigned short* __restrict__ ws_y,
        const float* __restrict__ ws_e, const float* __restrict__ stats,
        float* __restrict__ out)
{
    int tid = threadIdx.x;
    int wave = tid >> 6, lane = tid & 63;
    int kg = lane & 15, ns = lane >> 4;
    int b = blockIdx.y;
    int n0 = blockIdx.x * 256;
    float mx = stats[b*2], rs = stats[b*2+1];
    float acc[8] = {0,0,0,0,0,0,0,0};
    for (int it = 0; it < 16; it++){
        int n = n0 + it*16 + wave*4 + ns;
        float wgt = __expf(ws_e[b*NPOS + n] - mx) * rs;
        uint4 yv = *((const uint4*)(ws_y + (((size_t)b*NPOS + n)*DDIM + kg*8)));
        acc[0] += wgt * bf2f(yv.x & 0xffffu); acc[1] += wgt * bf2f(yv.x >> 16);
        acc[2] += wgt * bf2f(yv.y & 0xffffu); acc[3] += wgt * bf2f(yv.y >> 16);
        acc[4] += wgt * bf2f(yv.z & 0xffffu); acc[5] += wgt * bf2f(yv.z >> 16);
        acc[6] += wgt * bf2f(yv.w & 0xffffu); acc[7] += wgt * bf2f(yv.w >> 16);
    }
    #pragma unroll
    for (int j = 0; j < 8; j++){
        acc[j] += __shfl_xor(acc[j], 16);
        acc[j] += __shfl_xor(acc[j], 32);
    }
    if (lane < 16){
        #pragma unroll
        for (int j = 0; j < 8; j++)
            atomicAdd(&out[b*128 + lane*8 + j], acc[j]);
    }
}

extern "C" void kernel_launch(void* const* d_in, const int* in_sizes, int n_in,
                              void* d_out, int out_size, void* d_ws, size_t ws_size,
                              hipStream_t stream)
{
    const int*   seq = (const int*)d_in[0];
    const float* emb = (const float*)d_in[1];
    const float* cw  = (const float*)d_in[2];
    const float* cb  = (const float*)d_in[3];
    const float* Wa  = (const float*)d_in[4];
    const float* va  = (const float*)d_in[5];
    float* out = (float*)d_out;

    unsigned short* ws_y = (unsigned short*)d_ws;                       // 128*2048*128 bf16 = 64 MiB
    float* ws_e  = (float*)((char*)d_ws + (size_t)67108864);            // 128*2048 f32 = 1 MiB
    float* stats = (float*)((char*)d_ws + (size_t)67108864 + 1048576);  // 128*2 f32

    k0_conv   <<<512,          256, 0, stream>>>(seq, emb, cw, cb, ws_y);
    k1_gemm   <<<dim3(4,128),  256, 0, stream>>>(ws_y, Wa, va, ws_e);
    k2_softmax<<<128,          256, 0, stream>>>(ws_e, stats, out);
    k3_ctx    <<<dim3(8,128),  256, 0, stream>>>(ws_y, ws_e, stats, out);
}

// Round 3
// 134.406 us; speedup vs baseline: 1.2507x; 1.2507x over previous
//
#include <hip/hip_runtime.h>
#include <hip/hip_bf16.h>

#define B_   128
#define LSEQ 8194
#define NPOS 2048
#define DDIM 128

typedef __attribute__((ext_vector_type(8))) short bf16x8;
typedef __attribute__((ext_vector_type(4))) float f32x4;

static __device__ __forceinline__ short f2bf(float f){
    union { __hip_bfloat16 h; short s; } u; u.h = __float2bfloat16(f); return u.s;
}
static __device__ __forceinline__ float tanh_fast(float x){
    float ex = __expf(2.0f * x);
    return 1.0f - __fdividef(2.0f, ex + 1.0f);
}

// KA: fused conv + attention-GEMM -> e[b,n] only. y2 tiles live in LDS only.
__global__ __launch_bounds__(256, 2) void ka_conv_gemm(
        const int* __restrict__ seq, const float* __restrict__ emb,
        const float* __restrict__ cw, const float* __restrict__ cb,
        const float* __restrict__ Wa, const float* __restrict__ va,
        float* __restrict__ ws_e)
{
    __shared__ float2 tbl[3][26][17];          // pad 16->17: unpadded bank = 2*cp mod 32 (letter-independent)
    __shared__ int    seqw[4][520];            // 4 section windows of 514 letters
    __shared__ unsigned short ylds[64][136];   // [n][k] tile, padded
    __shared__ float va_lds[128];

    int tid = threadIdx.x;
    int b   = blockIdx.y;
    int n0  = blockIdx.x * 512;

    if (tid < 128) va_lds[tid] = va[tid];

    // per-letter tap tables: tbl[t][l][cp] = (emb[l].cw[2cp,:,t], emb[l].cw[2cp+1,:,t])
    for (int idx = tid; idx < 3*26*16; idx += 256){
        int k = idx / (26*16);
        int rem = idx - k*26*16;
        int l = rem >> 4;
        int cp = rem & 15;
        int c0 = cp*2;
        float v0 = 0.f, v1 = 0.f;
        #pragma unroll
        for (int i = 0; i < 5; i++){
            float e = emb[l*5 + i];
            v0 += cw[(c0*5 + i)*3 + k] * e;
            v1 += cw[((c0+1)*5 + i)*3 + k] * e;
        }
        if (k == 2){ v0 += cb[c0]; v1 += cb[c0+1]; }
        tbl[k][l][cp] = make_float2(v0, v1);
    }
    const int* sb = seq + (size_t)b * LSEQ;
    for (int i = tid; i < 4*514; i += 256){
        int s = i / 514, off = i - s*514;
        seqw[s][off] = sb[s*2048 + n0 + off];
    }

    int wave = tid >> 6, lane = tid & 63;
    int m = lane & 15, q = lane >> 4;

    // W_a A-fragments in registers: lane holds W[dt*16+m][ki*32 + q*8 + j]
    bf16x8 wf[8][4];
    #pragma unroll
    for (int dt = 0; dt < 8; dt++){
        #pragma unroll
        for (int ki = 0; ki < 4; ki++){
            const float* wp = Wa + (dt*16 + m)*128 + ki*32 + q*8;
            float4 a  = *((const float4*)wp);
            float4 b4 = *((const float4*)(wp + 4));
            bf16x8 f;
            f[0]=f2bf(a.x);  f[1]=f2bf(a.y);  f[2]=f2bf(a.z);  f[3]=f2bf(a.w);
            f[4]=f2bf(b4.x); f[5]=f2bf(b4.y); f[6]=f2bf(b4.z); f[7]=f2bf(b4.w);
            wf[dt][ki] = f;
        }
    }
    __syncthreads();

    for (int sub = 0; sub < 8; sub++){
        // generate 64x128 y2 tile into LDS (bf16)
        #pragma unroll
        for (int j = 0; j < 4; j++){
            int idx = tid + j*256;
            int row = idx >> 4, cp = idx & 15;
            int nl = sub*64 + row;
            float res[8];
            #pragma unroll
            for (int s = 0; s < 4; s++){
                int l1 = seqw[s][nl], l2 = seqw[s][nl+1], l3 = seqw[s][nl+2];
                float2 g0 = tbl[0][l1][cp];
                float2 g1 = tbl[1][l2][cp];
                float2 g2 = tbl[2][l3][cp];
                res[s]   = fmaxf(g0.x + g1.x + g2.x, 0.f);   // c=2cp,   k=8cp+s
                res[4+s] = fmaxf(g0.y + g1.y + g2.y, 0.f);   // c=2cp+1, k=8cp+4+s
            }
            union { __hip_bfloat162 h; unsigned int u; } p0,p1,p2,p3;
            p0.h = __float22bfloat162_rn(make_float2(res[0],res[1]));
            p1.h = __float22bfloat162_rn(make_float2(res[2],res[3]));
            p2.h = __float22bfloat162_rn(make_float2(res[4],res[5]));
            p3.h = __float22bfloat162_rn(make_float2(res[6],res[7]));
            uint4 o; o.x = p0.u; o.y = p1.u; o.z = p2.u; o.w = p3.u;
            *((uint4*)&ylds[row][cp*8]) = o;
        }
        __syncthreads();

        f32x4 acc[8];
        #pragma unroll
        for (int dt = 0; dt < 8; dt++) acc[dt] = (f32x4){0.f,0.f,0.f,0.f};
        #pragma unroll
        for (int ki = 0; ki < 4; ki++){
            bf16x8 bfrag = *((const bf16x8*)&ylds[wave*16 + m][ki*32 + q*8]);
            #pragma unroll
            for (int dt = 0; dt < 8; dt++)
                acc[dt] = __builtin_amdgcn_mfma_f32_16x16x32_bf16(wf[dt][ki], bfrag, acc[dt], 0, 0, 0);
        }
        float epart = 0.f;
        #pragma unroll
        for (int dt = 0; dt < 8; dt++){
            float4 vv = *((const float4*)&va_lds[dt*16 + q*4]);
            epart += vv.x * tanh_fast(acc[dt][0]);
            epart += vv.y * tanh_fast(acc[dt][1]);
            epart += vv.z * tanh_fast(acc[dt][2]);
            epart += vv.w * tanh_fast(acc[dt][3]);
        }
        epart += __shfl_xor(epart, 16);
        epart += __shfl_xor(epart, 32);
        if (lane < 16)
            ws_e[b*NPOS + n0 + sub*64 + wave*16 + lane] = epart;
        __syncthreads();
    }
}

// KB: softmax + pool with y2 regenerated in fp32 from seq + tap tables.
// One block per (b, d-half). Direct stores, no atomics, no out pre-state.
__global__ __launch_bounds__(256) void kb_softmax_ctx(
        const int* __restrict__ seq, const float* __restrict__ emb,
        const float* __restrict__ cw, const float* __restrict__ cb,
        const float* __restrict__ ws_e, float* __restrict__ out)
{
    __shared__ float2 tbl[3][26][17];
    __shared__ int    seqf[4][2052];    // full section windows (2050 letters each)
    __shared__ float  wlds[2048];
    __shared__ float  red[4], red2[4];
    __shared__ float  red3[4][8][8];

    int tid = threadIdx.x;
    int b = blockIdx.y;
    int h = blockIdx.x;                 // d-half: dims [h*64, h*64+64)

    for (int idx = tid; idx < 3*26*16; idx += 256){
        int k = idx / (26*16);
        int rem = idx - k*26*16;
        int l = rem >> 4;
        int cp = rem & 15;
        int c0 = cp*2;
        float v0 = 0.f, v1 = 0.f;
        #pragma unroll
        for (int i = 0; i < 5; i++){
            float e = emb[l*5 + i];
            v0 += cw[(c0*5 + i)*3 + k] * e;
            v1 += cw[((c0+1)*5 + i)*3 + k] * e;
        }
        if (k == 2){ v0 += cb[c0]; v1 += cb[c0+1]; }
        tbl[k][l][cp] = make_float2(v0, v1);
    }
    const int* sb = seq + (size_t)b * LSEQ;
    for (int i = tid; i < 4*2050; i += 256){
        int s = i / 2050, off = i - s*2050;
        seqf[s][off] = sb[s*2048 + off];
    }

    // softmax stats from ws_e row (each thread caches its 8 entries)
    const float* e = ws_e + b*NPOS;
    float ev[8];
    #pragma unroll
    for (int r = 0; r < 8; r++) ev[r] = e[tid + r*256];

    int wave = tid >> 6, lane = tid & 63;
    float mx = -1e30f;
    #pragma unroll
    for (int r = 0; r < 8; r++) mx = fmaxf(mx, ev[r]);
    #pragma unroll
    for (int off = 32; off >= 1; off >>= 1) mx = fmaxf(mx, __shfl_xor(mx, off));
    if (lane == 0) red[wave] = mx;
    __syncthreads();
    mx = fmaxf(fmaxf(red[0], red[1]), fmaxf(red[2], red[3]));
    float sum = 0.f;
    #pragma unroll
    for (int r = 0; r < 8; r++) sum += __expf(ev[r] - mx);
    #pragma unroll
    for (int off = 32; off >= 1; off >>= 1) sum += __shfl_xor(sum, off);
    if (lane == 0) red2[wave] = sum;
    __syncthreads();
    float rs = 1.0f / (red2[0] + red2[1] + red2[2] + red2[3]);
    #pragma unroll
    for (int r = 0; r < 8; r++) wlds[tid + r*256] = __expf(ev[r] - mx) * rs;
    __syncthreads();   // covers tbl, seqf, wlds

    // pool: thread (g, nn) owns dims d = h*64 + g*8 + j over n = it*32 + nn
    int g = tid & 7, nn = tid >> 3;
    int cp = h*8 + g;
    float acc[8] = {0,0,0,0,0,0,0,0};
    for (int it = 0; it < 64; it++){
        int n = it*32 + nn;
        float wgt = wlds[n];
        #pragma unroll
        for (int s = 0; s < 4; s++){
            int l1 = seqf[s][n], l2 = seqf[s][n+1], l3 = seqf[s][n+2];
            float2 g0 = tbl[0][l1][cp];
            float2 g1 = tbl[1][l2][cp];
            float2 g2 = tbl[2][l3][cp];
            acc[s]   += wgt * fmaxf(g0.x + g1.x + g2.x, 0.f);
            acc[4+s] += wgt * fmaxf(g0.y + g1.y + g2.y, 0.f);
        }
    }
    // reduce over nn: bits 3,4,5 of lane, then across waves via LDS
    #pragma unroll
    for (int j = 0; j < 8; j++){
        acc[j] += __shfl_xor(acc[j], 8);
        acc[j] += __shfl_xor(acc[j], 16);
        acc[j] += __shfl_xor(acc[j], 32);
    }
    if (lane < 8){
        #pragma unroll
        for (int j = 0; j < 8; j++) red3[wave][lane][j] = acc[j];
    }
    __syncthreads();
    if (tid < 64){
        int gg = tid >> 3, jj = tid & 7;
        out[b*128 + h*64 + tid] =
            red3[0][gg][jj] + red3[1][gg][jj] + red3[2][gg][jj] + red3[3][gg][jj];
    }
}

extern "C" void kernel_launch(void* const* d_in, const int* in_sizes, int n_in,
                              void* d_out, int out_size, void* d_ws, size_t ws_size,
                              hipStream_t stream)
{
    const int*   seq = (const int*)d_in[0];
    const float* emb = (const float*)d_in[1];
    const float* cw  = (const float*)d_in[2];
    const float* cb  = (const float*)d_in[3];
    const float* Wa  = (const float*)d_in[4];
    const float* va  = (const float*)d_in[5];
    float* out = (float*)d_out;

    float* ws_e = (float*)d_ws;    // 128*2048 f32 = 1 MiB

    ka_conv_gemm  <<<dim3(4,128), 256, 0, stream>>>(seq, emb, cw, cb, Wa, va, ws_e);
    kb_softmax_ctx<<<dim3(2,128), 256, 0, stream>>>(seq, emb, cw, cb, ws_e, out);
}